// Round 1
// baseline (797.716 us; speedup 1.0000x reference)
//
#include <hip/hip_runtime.h>
#include <math.h>

// SpectralConv3d: direct truncated DFTs instead of full FFTs.
// x: (8,32,32,96,96) f32; Wr/Wi: (32,32,8,16,16) f32; out: (8,32,32,96,96) f32.
// Pipeline:
//   K1 fwd2d : per (b,c,t): W-DFT (96->16 modes) then H-DFT (96->16)      -> X2 [b][c][t][kh][kw]
//   K2 fwdT  : T-DFT (32->8 modes)                                        -> X3 [b][c][kt][kh][kw]
//   K3 mix   : out_ft[b,d,m] = scale * sum_c X3[b,c,m]*(Wr+iWi)[c,d,m]    -> Cf
//   K4 invT  : T expand (8->32), e^{+i}                                   -> D  [b][d][t][kh][kw]
//   K5 inv2d : H expand (16->96) then c2r along W (Re(G0)+2*sum)          -> out
// Ortho norms: fwd 1/sqrt(THW) * inv 1/sqrt(THW) = 1/294912, folded into K3.

#define B_   8
#define CIN  32
#define COUT 32
#define T_   32
#define H_   96
#define W_   96
#define MT   8
#define MS   16

__device__ __forceinline__ void build_tw96(float* twc, float* tws, int tid, int nthreads) {
  // twc[k*96+n] = cos(2*pi*k*n/96), tws = sin(...), k in [0,16), n in [0,96)
  for (int i = tid; i < MS * 96; i += nthreads) {
    int k = i / 96, n = i - k * 96;
    int p = (k * n) % 96;
    float ang = (float)p * (6.2831853071795864769f / 96.0f);
    float s, c;
    sincosf(ang, &s, &c);
    twc[i] = c; tws[i] = s;
  }
}

// ---------------- K1: forward W + H DFT per (b,c,t) ----------------
__global__ __launch_bounds__(256) void k_fwd2d(const float* __restrict__ x,
                                               float2* __restrict__ X2) {
  __shared__ __align__(16) float xs[96 * 97];       // pad 97: conflict-free stage1 reads
  __shared__ __align__(16) float2 y2[96 * 16];      // stage1 output [h][kw]
  __shared__ __align__(16) float twc[16 * 96];
  __shared__ __align__(16) float tws[16 * 96];
  const int tid = threadIdx.x;
  const int bct = blockIdx.x;                        // (b*32+c)*32 + t

  // stage x tile: float4 global loads, scalar LDS writes (97-stride kills b128 align)
  const float4* x4 = (const float4*)(x + (size_t)bct * (H_ * W_));
  for (int i4 = tid; i4 < H_ * W_ / 4; i4 += 256) {
    float4 v = x4[i4];
    int h = i4 / (W_ / 4);
    int wq = (i4 - h * (W_ / 4)) * 4;
    float* dst = &xs[h * 97 + wq];
    dst[0] = v.x; dst[1] = v.y; dst[2] = v.z; dst[3] = v.w;
  }
  build_tw96(twc, tws, tid, 256);
  __syncthreads();

  // stage 1: y[h][kw] = sum_w x[h][w] * e^{-2pi i kw w/96}; thread = (h, kw-half)
  if (tid < 192) {
    int h = tid >> 1, g = tid & 1;
    float ar[8], ai[8];
#pragma unroll
    for (int j = 0; j < 8; j++) { ar[j] = 0.f; ai[j] = 0.f; }
    const float* xrow = &xs[h * 97];
    const float2* twc2 = (const float2*)twc;
    const float2* tws2 = (const float2*)tws;
    for (int w2 = 0; w2 < 48; w2++) {
      float x0 = xrow[2 * w2];
      float x1 = xrow[2 * w2 + 1];
#pragma unroll
      for (int j = 0; j < 8; j++) {
        int kw = g * 8 + j;
        float2 c = twc2[kw * 48 + w2];
        float2 s = tws2[kw * 48 + w2];
        ar[j] = fmaf(x0, c.x, fmaf(x1, c.y, ar[j]));
        ai[j] = fmaf(-x0, s.x, fmaf(-x1, s.y, ai[j]));
      }
    }
#pragma unroll
    for (int j = 0; j < 8; j++) y2[h * 16 + g * 8 + j] = make_float2(ar[j], ai[j]);
  }
  __syncthreads();

  // stage 2: X2[kh][kw] = sum_h y[h][kw] * e^{-2pi i kh h/96}; thread = (kh,kw)
  {
    int kw = tid & 15, kh = tid >> 4;
    float ar = 0.f, ai = 0.f;
    for (int h = 0; h < 96; h++) {
      float2 v = y2[h * 16 + kw];
      float c = twc[kh * 96 + h];
      float s = tws[kh * 96 + h];
      // (vr + i vi)(c - i s)
      ar = fmaf(v.x, c, fmaf(v.y, s, ar));
      ai = fmaf(v.y, c, fmaf(-v.x, s, ai));
    }
    X2[(size_t)bct * 256 + tid] = make_float2(ar, ai);
  }
}

// ---------------- K2: forward T DFT per (b,c) ----------------
__global__ __launch_bounds__(256) void k_fwdT(const float2* __restrict__ X2,
                                              float2* __restrict__ X3) {
  __shared__ float twtc[MT * T_], twts[MT * T_];
  const int tid = threadIdx.x;
  const int bc = blockIdx.x;
  {
    int kt = tid / T_, t = tid - kt * T_;
    int p = (kt * t) & 31;
    float ang = (float)p * (6.2831853071795864769f / 32.0f);
    float s, c; sincosf(ang, &s, &c);
    twtc[tid] = c; twts[tid] = s;
  }
  __syncthreads();
  float ar[MT], ai[MT];
#pragma unroll
  for (int k = 0; k < MT; k++) { ar[k] = 0.f; ai[k] = 0.f; }
  const float2* src = X2 + (size_t)bc * (T_ * 256);
  for (int t = 0; t < T_; t++) {
    float2 v = src[t * 256 + tid];
#pragma unroll
    for (int k = 0; k < MT; k++) {
      float c = twtc[k * T_ + t], s = twts[k * T_ + t];
      ar[k] = fmaf(v.x, c, fmaf(v.y, s, ar[k]));   // e^{-i}
      ai[k] = fmaf(v.y, c, fmaf(-v.x, s, ai[k]));
    }
  }
  float2* dst = X3 + (size_t)bc * (MT * 256);
#pragma unroll
  for (int k = 0; k < MT; k++) dst[k * 256 + tid] = make_float2(ar[k], ai[k]);
}

// ---------------- K3: channel mix per (b,d), threads over modes ----------------
__global__ __launch_bounds__(256) void k_mix(const float2* __restrict__ X3,
                                             const float* __restrict__ Wr,
                                             const float* __restrict__ Wi,
                                             float2* __restrict__ Cf) {
  const int tid = threadIdx.x;
  const int b = blockIdx.x >> 5;
  const int d = blockIdx.x & 31;
  const float scale = 1.0f / (float)(T_ * H_ * W_);  // combined ortho factor
  for (int chunk = 0; chunk < 8; chunk++) {
    int m = chunk * 256 + tid;
    float ar = 0.f, ai = 0.f;
    for (int c = 0; c < CIN; c++) {
      float2 xv = X3[((size_t)(b * CIN + c)) * 2048 + m];
      float wr = Wr[((size_t)(c * COUT + d)) * 2048 + m];
      float wi = Wi[((size_t)(c * COUT + d)) * 2048 + m];
      ar = fmaf(xv.x, wr, fmaf(-xv.y, wi, ar));
      ai = fmaf(xv.x, wi, fmaf(xv.y, wr, ai));
    }
    Cf[((size_t)(b * COUT + d)) * 2048 + m] = make_float2(ar * scale, ai * scale);
  }
}

// ---------------- K4: inverse T expand per (b,d) ----------------
__global__ __launch_bounds__(256) void k_invT(const float2* __restrict__ Cf,
                                              float2* __restrict__ D) {
  __shared__ float twtc[MT * T_], twts[MT * T_];
  const int tid = threadIdx.x;
  const int bd = blockIdx.x;
  {
    int kt = tid / T_, t = tid - kt * T_;
    int p = (kt * t) & 31;
    float ang = (float)p * (6.2831853071795864769f / 32.0f);
    float s, c; sincosf(ang, &s, &c);
    twtc[tid] = c; twts[tid] = s;
  }
  __syncthreads();
  float cr[MT], ci[MT];
#pragma unroll
  for (int k = 0; k < MT; k++) {
    float2 v = Cf[(size_t)bd * 2048 + k * 256 + tid];
    cr[k] = v.x; ci[k] = v.y;
  }
  for (int t = 0; t < T_; t++) {
    float ar = 0.f, ai = 0.f;
#pragma unroll
    for (int k = 0; k < MT; k++) {
      float c = twtc[k * T_ + t], s = twts[k * T_ + t];
      ar = fmaf(cr[k], c, fmaf(-ci[k], s, ar));    // e^{+i}
      ai = fmaf(cr[k], s, fmaf(ci[k], c, ai));
    }
    D[((size_t)bd * T_ + t) * 256 + tid] = make_float2(ar, ai);
  }
}

// ---------------- K5: inverse H expand + c2r W per (b,d,t) ----------------
__global__ __launch_bounds__(256) void k_inv2d(const float2* __restrict__ D,
                                               float* __restrict__ out) {
  __shared__ __align__(16) float2 dm[256];          // [kh][kw]
  __shared__ __align__(16) float2 g2[96 * 16];      // [h][kw]
  __shared__ __align__(16) float twc[16 * 96];
  __shared__ __align__(16) float tws[16 * 96];
  const int tid = threadIdx.x;
  const int bdt = blockIdx.x;                        // (b*32+d)*32 + t
  dm[tid] = D[(size_t)bdt * 256 + tid];
  build_tw96(twc, tws, tid, 256);
  __syncthreads();

  // stage A: g2[h][kw] = sum_kh dm[kh][kw] * e^{+2pi i kh h/96}
  if (tid < 192) {
    int h = tid >> 1, g = tid & 1;
    float ar[8], ai[8];
#pragma unroll
    for (int j = 0; j < 8; j++) { ar[j] = 0.f; ai[j] = 0.f; }
    for (int kh = 0; kh < 16; kh++) {
      float c = twc[kh * 96 + h];
      float s = tws[kh * 96 + h];
#pragma unroll
      for (int j = 0; j < 8; j++) {
        float2 v = dm[kh * 16 + g * 8 + j];
        ar[j] = fmaf(v.x, c, fmaf(-v.y, s, ar[j]));  // (vr+ivi)(c+is)
        ai[j] = fmaf(v.x, s, fmaf(v.y, c, ai[j]));
      }
    }
#pragma unroll
    for (int j = 0; j < 8; j++) g2[h * 16 + g * 8 + j] = make_float2(ar[j], ai[j]);
  }
  __syncthreads();

  // stage B: c2r along W. out[h][w] = Re(g2[h][0]) + 2*sum_{kw>=1}(gr cos - gi sin)
  float4* orow4 = (float4*)(out + (size_t)bdt * (H_ * W_));
  for (int pos4 = tid; pos4 < H_ * W_ / 4; pos4 += 256) {
    int h = pos4 / 24;
    int w0 = (pos4 - h * 24) * 4;
    const float2* grow = &g2[h * 16];
    float acc[4] = {0.f, 0.f, 0.f, 0.f};
#pragma unroll
    for (int kw = 1; kw < 16; kw++) {
      float2 v = grow[kw];
      const float* cbase = &twc[kw * 96 + w0];
      const float* sbase = &tws[kw * 96 + w0];
#pragma unroll
      for (int q = 0; q < 4; q++) {
        acc[q] = fmaf(v.x, cbase[q], fmaf(-v.y, sbase[q], acc[q]));
      }
    }
    float g0 = grow[0].x;   // c2r ignores Im of bin 0
    float4 o;
    o.x = fmaf(2.f, acc[0], g0);
    o.y = fmaf(2.f, acc[1], g0);
    o.z = fmaf(2.f, acc[2], g0);
    o.w = fmaf(2.f, acc[3], g0);
    orow4[pos4] = o;
  }
}

extern "C" void kernel_launch(void* const* d_in, const int* in_sizes, int n_in,
                              void* d_out, int out_size, void* d_ws, size_t ws_size,
                              hipStream_t stream) {
  const float* x  = (const float*)d_in[0];
  const float* Wr = (const float*)d_in[1];
  const float* Wi = (const float*)d_in[2];
  float* out = (float*)d_out;

  // workspace layout (float2 units): X2 2097152 | X3 524288 | Cf 524288 | D 2097152
  float2* X2 = (float2*)d_ws;
  float2* X3 = X2 + 2097152;
  float2* Cf = X3 + 524288;
  float2* Dd = Cf + 524288;

  k_fwd2d<<<B_ * CIN * T_, 256, 0, stream>>>(x, X2);
  k_fwdT <<<B_ * CIN,      256, 0, stream>>>(X2, X3);
  k_mix  <<<B_ * COUT,     256, 0, stream>>>(X3, Wr, Wi, Cf);
  k_invT <<<B_ * COUT,     256, 0, stream>>>(Cf, Dd);
  k_inv2d<<<B_ * COUT * T_, 256, 0, stream>>>(Dd, out);
}